// Round 10
// baseline (26.630 us; speedup 1.0000x reference)
//
#include <hip/hip_runtime.h>
#include <float.h>

#define NPTS 4096
#define NB   8

typedef __bf16 bf16x8 __attribute__((ext_vector_type(8)));
typedef float  f32x16 __attribute__((ext_vector_type(16)));

__device__ __forceinline__ float min3f(float a, float b, float c) {
    return fminf(fminf(a, b), c);   // clang fuses to v_min3_f32
}

__device__ __forceinline__ void split_bf(float v, __bf16& hi, __bf16& lo) {
    hi = (__bf16)v;
    lo = (__bf16)(v - (float)hi);
}

// ---------------- main: MFMA distance tiles + in-register col-min ------------
// grid (64, 16): blockIdx.x = rowgrp*8 + jgroup, blockIdx.y = bdir = b*2+dir.
// dir0: rows=gts, cols=preds; dir1 swapped. Block: 512 rows (4 waves x 128)
// x 512 cols. Split-bf16 rank-13 K-expansion, one v_mfma_f32_32x32x16_bf16 per
// 32x32 tile (compute identical to round 8; only the part layout changed to
// [bdir][col][band] so comb reads are contiguous).
__global__ void __launch_bounds__(256, 4) chamfer_mfma(
    const float* __restrict__ preds,
    const float* __restrict__ gts,
    float* __restrict__ part)
{
    __shared__ __align__(16) __bf16 Btab[2][512][8];   // 16 KB
    __shared__ float pmLds[4][512];                    // 8 KB

    const int rowgrp = blockIdx.x >> 3;
    const int jgroup = blockIdx.x & 7;
    const int bdir   = blockIdx.y;
    const int b = bdir >> 1, dir = bdir & 1;

    const float* rows = ((dir == 0) ? gts   : preds) + (size_t)b * NPTS * 3;
    const float* cols = ((dir == 0) ? preds : gts)   + (size_t)b * NPTS * 3;

    const int tid  = threadIdx.x;
    const int lane = tid & 63;
    const int w    = tid >> 6;
    const __bf16 one = (__bf16)1.0f, zero = (__bf16)0.0f;

    // stage B table: 512 cols, split-bf16 of (-2x,-2y,-2z) and h
    #pragma unroll
    for (int r = 0; r < 2; ++r) {
        const int c = tid + r * 256;
        const float* p = cols + (size_t)(jgroup * 512 + c) * 3;
        const float x = p[0], y = p[1], z = p[2];
        const float h = x * x + y * y + z * z;
        __bf16 uh, ul, vh, vl, wh, wl, hh, hl;
        split_bf(-2.0f * x, uh, ul);
        split_bf(-2.0f * y, vh, vl);
        split_bf(-2.0f * z, wh, wl);
        split_bf(h, hh, hl);
        bf16x8 b0, b1;
        b0[0] = uh; b0[1] = ul; b0[2] = uh; b0[3] = vh;
        b0[4] = vl; b0[5] = vh; b0[6] = wh; b0[7] = wl;
        b1[0] = wh; b1[1] = one; b1[2] = one; b1[3] = hh;
        b1[4] = hl; b1[5] = zero; b1[6] = zero; b1[7] = zero;
        *(bf16x8*)&Btab[0][c][0] = b0;
        *(bf16x8*)&Btab[1][c][0] = b1;
    }

    // A fragments: 4 i-blocks x 32 rows; lane half selects k0-7 / k8-15 slots
    bf16x8 afr[4];
    const int rbase = rowgrp * 512 + w * 128;
    #pragma unroll
    for (int ib = 0; ib < 4; ++ib) {
        const float* g = rows + (size_t)(rbase + ib * 32 + (lane & 31)) * 3;
        const float x = g[0], y = g[1], z = g[2];
        const float h = x * x + y * y + z * z;
        __bf16 xh, xl, yh, yl, zh, zl, hh, hl;
        split_bf(x, xh, xl);
        split_bf(y, yh, yl);
        split_bf(z, zh, zl);
        split_bf(h, hh, hl);
        bf16x8 a;
        if (lane < 32) {
            a[0] = xh; a[1] = xh; a[2] = xl; a[3] = yh;
            a[4] = yh; a[5] = yl; a[6] = zh; a[7] = zh;
        } else {
            a[0] = zl; a[1] = hh; a[2] = hl; a[3] = one;
            a[4] = one; a[5] = zero; a[6] = zero; a[7] = zero;
        }
        afr[ib] = a;
    }
    __syncthreads();

    f32x16 zc = 0.0f;    // C = 0 (everything folded into K)

    for (int jt = 0; jt < 16; ++jt) {
        const bf16x8 bfr = *(const bf16x8*)&Btab[lane >> 5][jt * 32 + (lane & 31)][0];
        float pmin = FLT_MAX;
        #pragma unroll
        for (int ib = 0; ib < 4; ++ib) {
            f32x16 d = __builtin_amdgcn_mfma_f32_32x32x16_bf16(afr[ib], bfr, zc, 0, 0, 0);
            const float m0 = min3f(d[0],  d[1],  d[2]);
            const float m1 = min3f(d[3],  d[4],  d[5]);
            const float m2 = min3f(d[6],  d[7],  d[8]);
            const float m3 = min3f(d[9],  d[10], d[11]);
            const float m4 = min3f(d[12], d[13], d[14]);
            const float mm = min3f(min3f(m0, m1, m2), fminf(m3, m4), d[15]);
            pmin = fminf(pmin, mm);
        }
        // combine the two lane-half row-groups -> 128-row min per col
        pmin = fminf(pmin, __shfl_xor(pmin, 32, 64));
        if (lane < 32) pmLds[w][jt * 32 + (lane & 31)] = pmin;
    }
    __syncthreads();

    // cross-wave (4 row-bands of 128) min -> 512-row band min,
    // write transposed: part[(bdir*NPTS + col)*8 + rowgrp]
    float* wsout = part + (size_t)(bdir * NPTS + jgroup * 512) * 8 + rowgrp;
    #pragma unroll
    for (int r = 0; r < 2; ++r) {
        const int idx = tid + r * 256;
        wsout[(size_t)idx * 8] =
            fminf(min3f(pmLds[0][idx], pmLds[1][idx], pmLds[2][idx]),
                  pmLds[3][idx]);
    }
}

// ---------------- combine: one block per batch, vectorized band reads --------
// grid 8, block 1024. Each thread: 4 cols/dir x 8 contiguous band-mins
// (8 x float4, fully coalesced), min-of-8 in 4 ops, fixed-order block reduce,
// plain store (overwrites poison; deterministic).
__global__ void __launch_bounds__(1024) chamfer_comb(
    const float* __restrict__ part, float* __restrict__ out)
{
    const int b   = blockIdx.x;
    const int tid = threadIdx.x;

    float sum = 0.0f;
    #pragma unroll
    for (int d = 0; d < 2; ++d) {
        const float4* p4 = (const float4*)(part
            + (size_t)((b * 2 + d) * NPTS + tid * 4) * 8);
        #pragma unroll
        for (int c = 0; c < 4; ++c) {
            const float4 v0 = p4[c * 2];
            const float4 v1 = p4[c * 2 + 1];
            float m = fminf(min3f(v0.x, v0.y, v0.z), min3f(v0.w, v1.x, v1.y));
            sum += min3f(m, v1.z, v1.w);
        }
    }

    __shared__ float red[1024];
    red[tid] = sum;
    __syncthreads();
    #pragma unroll
    for (int off = 512; off >= 1; off >>= 1) {
        if (tid < off) red[tid] += red[tid + off];
        __syncthreads();
    }
    if (tid == 0) out[b] = red[0];
}

extern "C" void kernel_launch(void* const* d_in, const int* in_sizes, int n_in,
                              void* d_out, int out_size, void* d_ws, size_t ws_size,
                              hipStream_t stream)
{
    const float* preds = (const float*)d_in[0];
    const float* gts   = (const float*)d_in[1];
    float* out  = (float*)d_out;
    float* part = (float*)d_ws;                       // 16*4096*8 f32 = 2 MB

    chamfer_mfma<<<dim3(64, 16), 256, 0, stream>>>(preds, gts, part);
    chamfer_comb<<<8, 1024, 0, stream>>>(part, out);
}

// Round 11
// 21.824 us; speedup vs baseline: 1.2202x; 1.2202x over previous
//
#include <hip/hip_runtime.h>
#include <float.h>

#define NPTS 4096
#define NB   8

typedef __bf16 bf16x8 __attribute__((ext_vector_type(8)));
typedef float  f32x16 __attribute__((ext_vector_type(16)));

__device__ __forceinline__ float min3f(float a, float b, float c) {
    return fminf(fminf(a, b), c);   // clang fuses to v_min3_f32
}

__device__ __forceinline__ void split_bf(float v, __bf16& hi, __bf16& lo) {
    hi = (__bf16)v;
    lo = (__bf16)(v - (float)hi);
}

// ---------------- main: MFMA distance tiles + in-register col-min ------------
// grid (64, 16): blockIdx.x = rowgrp*8 + jgroup (rowgrp 0..7, jgroup 0..7),
// blockIdx.y = bdir = b*2+dir. dir0: rows=gts, cols=preds; dir1 swapped.
// Block: 512 rows (4 waves x 128) x 512 cols. Split-bf16 rank-13 K-expansion,
// one v_mfma_f32_32x32x16_bf16 per 32x32 tile. BYTE-IDENTICAL to round 8's
// verified best (21.9 us): part layout [bdir][band][col] keeps the epilogue
// store coalesced (round 10's [col][band] transpose cost 4.7 us in scatter).
__global__ void __launch_bounds__(256, 4) chamfer_mfma(
    const float* __restrict__ preds,
    const float* __restrict__ gts,
    float* __restrict__ part)
{
    __shared__ __align__(16) __bf16 Btab[2][512][8];   // 16 KB
    __shared__ float pmLds[4][512];                    // 8 KB

    const int rowgrp = blockIdx.x >> 3;
    const int jgroup = blockIdx.x & 7;
    const int bdir   = blockIdx.y;
    const int b = bdir >> 1, dir = bdir & 1;

    const float* rows = ((dir == 0) ? gts   : preds) + (size_t)b * NPTS * 3;
    const float* cols = ((dir == 0) ? preds : gts)   + (size_t)b * NPTS * 3;

    const int tid  = threadIdx.x;
    const int lane = tid & 63;
    const int w    = tid >> 6;
    const __bf16 one = (__bf16)1.0f, zero = (__bf16)0.0f;

    // stage B table: 512 cols, split-bf16 of (-2x,-2y,-2z) and h
    #pragma unroll
    for (int r = 0; r < 2; ++r) {
        const int c = tid + r * 256;
        const float* p = cols + (size_t)(jgroup * 512 + c) * 3;
        const float x = p[0], y = p[1], z = p[2];
        const float h = x * x + y * y + z * z;
        __bf16 uh, ul, vh, vl, wh, wl, hh, hl;
        split_bf(-2.0f * x, uh, ul);
        split_bf(-2.0f * y, vh, vl);
        split_bf(-2.0f * z, wh, wl);
        split_bf(h, hh, hl);
        bf16x8 b0, b1;
        b0[0] = uh; b0[1] = ul; b0[2] = uh; b0[3] = vh;
        b0[4] = vl; b0[5] = vh; b0[6] = wh; b0[7] = wl;
        b1[0] = wh; b1[1] = one; b1[2] = one; b1[3] = hh;
        b1[4] = hl; b1[5] = zero; b1[6] = zero; b1[7] = zero;
        *(bf16x8*)&Btab[0][c][0] = b0;
        *(bf16x8*)&Btab[1][c][0] = b1;
    }

    // A fragments: 4 i-blocks x 32 rows; lane half selects k0-7 / k8-15 slots
    bf16x8 afr[4];
    const int rbase = rowgrp * 512 + w * 128;
    #pragma unroll
    for (int ib = 0; ib < 4; ++ib) {
        const float* g = rows + (size_t)(rbase + ib * 32 + (lane & 31)) * 3;
        const float x = g[0], y = g[1], z = g[2];
        const float h = x * x + y * y + z * z;
        __bf16 xh, xl, yh, yl, zh, zl, hh, hl;
        split_bf(x, xh, xl);
        split_bf(y, yh, yl);
        split_bf(z, zh, zl);
        split_bf(h, hh, hl);
        bf16x8 a;
        if (lane < 32) {
            a[0] = xh; a[1] = xh; a[2] = xl; a[3] = yh;
            a[4] = yh; a[5] = yl; a[6] = zh; a[7] = zh;
        } else {
            a[0] = zl; a[1] = hh; a[2] = hl; a[3] = one;
            a[4] = one; a[5] = zero; a[6] = zero; a[7] = zero;
        }
        afr[ib] = a;
    }
    __syncthreads();

    f32x16 zc = 0.0f;    // C = 0 (everything folded into K)

    for (int jt = 0; jt < 16; ++jt) {
        const bf16x8 bfr = *(const bf16x8*)&Btab[lane >> 5][jt * 32 + (lane & 31)][0];
        float pmin = FLT_MAX;
        #pragma unroll
        for (int ib = 0; ib < 4; ++ib) {
            f32x16 d = __builtin_amdgcn_mfma_f32_32x32x16_bf16(afr[ib], bfr, zc, 0, 0, 0);
            const float m0 = min3f(d[0],  d[1],  d[2]);
            const float m1 = min3f(d[3],  d[4],  d[5]);
            const float m2 = min3f(d[6],  d[7],  d[8]);
            const float m3 = min3f(d[9],  d[10], d[11]);
            const float m4 = min3f(d[12], d[13], d[14]);
            const float mm = min3f(min3f(m0, m1, m2), fminf(m3, m4), d[15]);
            pmin = fminf(pmin, mm);
        }
        // combine the two lane-half row-groups -> 128-row min per col
        pmin = fminf(pmin, __shfl_xor(pmin, 32, 64));
        if (lane < 32) pmLds[w][jt * 32 + (lane & 31)] = pmin;
    }
    __syncthreads();

    // cross-wave (4 row-bands of 128) min -> 512-row band min, write part
    float* wsout = part + (size_t)(bdir * 8 + rowgrp) * NPTS + jgroup * 512;
    #pragma unroll
    for (int r = 0; r < 2; ++r) {
        const int idx = tid + r * 256;
        wsout[idx] = fminf(min3f(pmLds[0][idx], pmLds[1][idx], pmLds[2][idx]),
                           pmLds[3][idx]);
    }
}

// ---------------- combine: one block per batch, both dirs, plain store -------
// grid 8, block 1024 (vs round 8's 512: halves per-thread serial loads, more
// waves to hide latency on the 8 active CUs). For fixed (band,c) consecutive
// tids read consecutive floats -> coalesced. Fixed-order reduction ->
// deterministic; plain store overwrites poison.
__global__ void __launch_bounds__(1024) chamfer_comb(
    const float* __restrict__ part, float* __restrict__ out)
{
    const int b   = blockIdx.x;
    const int tid = threadIdx.x;

    float sum = 0.0f;
    #pragma unroll
    for (int dir = 0; dir < 2; ++dir) {
        const float* p0 = part + (size_t)(b * 2 + dir) * 8 * NPTS;
        #pragma unroll
        for (int c = 0; c < 4; ++c) {
            const int col = c * 1024 + tid;
            float m = p0[col];
            #pragma unroll
            for (int band = 1; band < 8; ++band)
                m = fminf(m, p0[(size_t)band * NPTS + col]);
            sum += m;
        }
    }

    __shared__ float red[1024];
    red[tid] = sum;
    __syncthreads();
    #pragma unroll
    for (int off = 512; off >= 1; off >>= 1) {
        if (tid < off) red[tid] += red[tid + off];
        __syncthreads();
    }
    if (tid == 0) out[b] = red[0];
}

extern "C" void kernel_launch(void* const* d_in, const int* in_sizes, int n_in,
                              void* d_out, int out_size, void* d_ws, size_t ws_size,
                              hipStream_t stream)
{
    const float* preds = (const float*)d_in[0];
    const float* gts   = (const float*)d_in[1];
    float* out  = (float*)d_out;
    float* part = (float*)d_ws;                       // 16*8*4096 f32 = 2 MB

    chamfer_mfma<<<dim3(64, 16), 256, 0, stream>>>(preds, gts, part);
    chamfer_comb<<<8, 1024, 0, stream>>>(part, out);
}